// Round 1
// 821.987 us; speedup vs baseline: 1.7010x; 1.7010x over previous
//
#include <hip/hip_runtime.h>
#include <float.h>
#include <math.h>

// Problem constants (fixed by setup_inputs)
constexpr int Bn = 131072;  // points
constexpr int Dn = 256;     // feature dim
constexpr int Kn = 1024;    // clusters
constexpr int Ln = 526;     // label dim
constexpr float EPSF = 1e-8f;

constexpr int CHUNK = 128;                    // members per fused-kernel block
constexpr int MAXCHUNKS = Bn / CHUNK + Kn;    // 2048: sum ceil(n_k/C) <= B/C + K

// ---- assign kernel tiling (split-f16 MFMA GEMM) ----
constexpr int BM  = 128;        // points per block
constexpr int BN  = 128;        // centroids per n-tile
constexpr int KC  = 32;         // K per chunk (f16 MFMA 16x16x32)
constexpr int NT  = Kn / BN;    // 8 n-tiles
constexpr int KCH = Dn / KC;    // 8 k-chunks
constexpr int NCH = NT * KCH;   // 64 chunks total
constexpr int LDH = 40;         // padded f16 row stride (80 B): rows rotate 20 banks
                                // -> ds_read_b128 over 16 rows = 2-way max (free)

typedef _Float16 f16x8 __attribute__((ext_vector_type(8)));
typedef _Float16 f16x4 __attribute__((ext_vector_type(4)));
typedef float    f32x4 __attribute__((ext_vector_type(4)));

union SMemU {
    _Float16 planes[2][4][BM][LDH];          // [buf][Ah,Al,Bh,Bl][row][d] = 81920 B
    struct { float t[BM][2]; int k[BM][2]; } red;
};

// ---------------- prep: c2[k] = sum(centroids[k]^2), rln[k] = sqrt(sum(rl[k]^2))
__global__ __launch_bounds__(256) void prep_kernel(
    const float* __restrict__ centroids, const float* __restrict__ rlabels,
    float* __restrict__ c2, float* __restrict__ rln)
{
    const int k = blockIdx.x;
    const int t = threadIdx.x;
    float v = centroids[k * Dn + t];            // Dn == blockDim
    float s1 = v * v;
    float s2 = 0.f;
    for (int i = t; i < Ln; i += 256) {
        float u = rlabels[(size_t)k * Ln + i];
        s2 += u * u;
    }
    for (int off = 32; off > 0; off >>= 1) {
        s1 += __shfl_down(s1, off, 64);
        s2 += __shfl_down(s2, off, 64);
    }
    __shared__ float red[8];
    const int wv = t >> 6;
    if ((t & 63) == 0) { red[wv * 2] = s1; red[wv * 2 + 1] = s2; }
    __syncthreads();
    if (t == 0) {
        c2[k]  = red[0] + red[2] + red[4] + red[6];
        rln[k] = sqrtf(red[1] + red[3] + red[5] + red[7]);
    }
}

// ---------------- assignment: split-f16 MFMA GEMM, 128 points x 1024 centroids.
// dot(p,c) computed as Ah*Bh + Ah*Bl + Al*Bh (f16 hi/lo split, fp32 accumulate):
// dropped Al*Bl term is ~2^-24 relative -> fp32-equivalent precision.
// t(b,k) = c2[k] - 2*dot; argmin_k t == argmin_k dist (x2 is row-constant).
__global__ __launch_bounds__(256, 2) void assign_kernel(
    const float* __restrict__ points, const float* __restrict__ centroids,
    const float* __restrict__ c2,
    float* __restrict__ o_assign, int* __restrict__ ws_assign,
    float* __restrict__ ws_tmin)
{
    __shared__ __align__(16) SMemU sm;
    const int tid  = threadIdx.x;
    const int lane = tid & 63;
    const int wid  = tid >> 6;
    const int wrow = wid >> 1;          // which 64-point half
    const int wcol = wid & 1;           // which 64-centroid half of the n-tile
    const int ln15 = lane & 15;
    const int koff = (lane >> 4) * 8;   // k-offset within 32-chunk for frags
    const int bm0  = blockIdx.x * BM;

    f32x4 acc[4][4];
#pragma unroll
    for (int i = 0; i < 4; ++i)
#pragma unroll
        for (int j = 0; j < 4; ++j)
#pragma unroll
            for (int r = 0; r < 4; ++r) acc[i][j][r] = 0.f;

    float mint[16];
    int   mink[16];
#pragma unroll
    for (int s = 0; s < 16; ++s) { mint[s] = FLT_MAX; mink[s] = 0; }

    // staging: 256 threads x 4 reps x float4 cover 128x32 fp32 per matrix
    float4 pa[4], pb[4];
    auto prefetch = [&](int t) {
        const int nt = t >> 3, kc = t & 7;
        const int dof = kc * KC;
#pragma unroll
        for (int rep = 0; rep < 4; ++rep) {
            const int idx = rep * 256 + tid;
            const int row = idx >> 3;
            const int c4  = (idx & 7) * 4;
            pa[rep] = *(const float4*)(points    + (size_t)(bm0 + row) * Dn + dof + c4);
            pb[rep] = *(const float4*)(centroids + (size_t)(nt * BN + row) * Dn + dof + c4);
        }
    };
    auto writeLDS = [&](int buf) {
#pragma unroll
        for (int rep = 0; rep < 4; ++rep) {
            const int idx = rep * 256 + tid;
            const int row = idx >> 3;
            const int c4  = (idx & 7) * 4;
            float4 v = pa[rep];
            f16x4 h, l;
            h.x = (_Float16)v.x; l.x = (_Float16)(v.x - (float)h.x);
            h.y = (_Float16)v.y; l.y = (_Float16)(v.y - (float)h.y);
            h.z = (_Float16)v.z; l.z = (_Float16)(v.z - (float)h.z);
            h.w = (_Float16)v.w; l.w = (_Float16)(v.w - (float)h.w);
            *(f16x4*)&sm.planes[buf][0][row][c4] = h;
            *(f16x4*)&sm.planes[buf][1][row][c4] = l;
            v = pb[rep];
            h.x = (_Float16)v.x; l.x = (_Float16)(v.x - (float)h.x);
            h.y = (_Float16)v.y; l.y = (_Float16)(v.y - (float)h.y);
            h.z = (_Float16)v.z; l.z = (_Float16)(v.z - (float)h.z);
            h.w = (_Float16)v.w; l.w = (_Float16)(v.w - (float)h.w);
            *(f16x4*)&sm.planes[buf][2][row][c4] = h;
            *(f16x4*)&sm.planes[buf][3][row][c4] = l;
        }
    };

    prefetch(0);
    writeLDS(0);
    __syncthreads();

    for (int t = 0; t < NCH; ++t) {
        const int buf = t & 1;
        const bool more = (t + 1) < NCH;
        if (more) prefetch(t + 1);

        // fragment loads: A row = lane&15, 8 consecutive k at (lane>>4)*8
        f16x8 ah[4], al[4], bh[4], bl[4];
#pragma unroll
        for (int mi = 0; mi < 4; ++mi) {
            const int ar = wrow * 64 + mi * 16 + ln15;
            ah[mi] = *(const f16x8*)&sm.planes[buf][0][ar][koff];
            al[mi] = *(const f16x8*)&sm.planes[buf][1][ar][koff];
        }
#pragma unroll
        for (int nj = 0; nj < 4; ++nj) {
            const int br = wcol * 64 + nj * 16 + ln15;
            bh[nj] = *(const f16x8*)&sm.planes[buf][2][br][koff];
            bl[nj] = *(const f16x8*)&sm.planes[buf][3][br][koff];
        }
#pragma unroll
        for (int mi = 0; mi < 4; ++mi)
#pragma unroll
            for (int nj = 0; nj < 4; ++nj) {
                acc[mi][nj] = __builtin_amdgcn_mfma_f32_16x16x32_f16(
                    al[mi], bh[nj], acc[mi][nj], 0, 0, 0);
                acc[mi][nj] = __builtin_amdgcn_mfma_f32_16x16x32_f16(
                    ah[mi], bl[nj], acc[mi][nj], 0, 0, 0);
                acc[mi][nj] = __builtin_amdgcn_mfma_f32_16x16x32_f16(
                    ah[mi], bh[nj], acc[mi][nj], 0, 0, 0);
            }

        if ((t & 7) == 7) {
            // n-tile complete: fold into running argmin using C/D layout
            // (col = lane&15 -> centroid, row = (lane>>4)*4 + reg -> point)
            const int nt = t >> 3;
            const int nb = nt * BN + wcol * 64 + ln15;
#pragma unroll
            for (int nj = 0; nj < 4; ++nj) {
                const int n = nb + nj * 16;
                const float c2n = c2[n];
#pragma unroll
                for (int mi = 0; mi < 4; ++mi)
#pragma unroll
                    for (int r = 0; r < 4; ++r) {
                        const float tv = fmaf(-2.f, acc[mi][nj][r], c2n);
                        const int s = mi * 4 + r;
                        if (tv < mint[s] || (tv == mint[s] && n < mink[s])) {
                            mint[s] = tv; mink[s] = n;
                        }
                        acc[mi][nj][r] = 0.f;
                    }
            }
        }

        if (more) {
            writeLDS(buf ^ 1);
            __syncthreads();
        }
    }

    // cross-lane argmin over the 16 centroid-columns (low 4 lane bits)
#pragma unroll
    for (int s = 0; s < 16; ++s) {
        float tv = mint[s]; int kv = mink[s];
#pragma unroll
        for (int off = 1; off < 16; off <<= 1) {
            const float to = __shfl_xor(tv, off, 64);
            const int   ko = __shfl_xor(kv, off, 64);
            if (to < tv || (to == tv && ko < kv)) { tv = to; kv = ko; }
        }
        mint[s] = tv; mink[s] = kv;
    }
    __syncthreads();   // all waves done reading planes; safe to reuse LDS
    if (ln15 == 0) {
        const int g = lane >> 4;
#pragma unroll
        for (int s = 0; s < 16; ++s) {
            const int pr = wrow * 64 + (s >> 2) * 16 + g * 4 + (s & 3);
            sm.red.t[pr][wcol] = mint[s];
            sm.red.k[pr][wcol] = mink[s];
        }
    }
    __syncthreads();
    if (tid < BM) {
        float bt = sm.red.t[tid][0];
        int   bk = sm.red.k[tid][0];
        const float t1 = sm.red.t[tid][1];
        const int   k1 = sm.red.k[tid][1];
        if (t1 < bt || (t1 == bt && k1 < bk)) { bt = t1; bk = k1; }
        o_assign[bm0 + tid]  = (float)bk;
        ws_assign[bm0 + tid] = bk;
        ws_tmin[bm0 + tid]   = bt;
    }
}

// ---------------- counting sort: histogram
__global__ __launch_bounds__(256) void count_kernel(
    const int* __restrict__ assigni, int* __restrict__ counts)
{
    const int p = blockIdx.x * 256 + threadIdx.x;
    atomicAdd(&counts[assigni[p]], 1);
}

// ---------------- exclusive scans over Kn=1024: counts and chunk counts
__global__ __launch_bounds__(1024) void scan_kernel(
    const int* __restrict__ counts, int* __restrict__ offsets,
    int* __restrict__ cursor, float* __restrict__ o_nn,
    int* __restrict__ chunk_off)
{
    __shared__ int s[Kn];
    const int t = threadIdx.x;
    const int c = counts[t];
    o_nn[t] = (float)c;
    s[t] = c;
    __syncthreads();
    for (int off = 1; off < Kn; off <<= 1) {
        const int u = (t >= off) ? s[t - off] : 0;
        __syncthreads();
        s[t] += u;
        __syncthreads();
    }
    const int excl = s[t] - c;
    offsets[t] = excl;
    cursor[t]  = excl;

    // second scan: chunks per cluster
    const int cc = (c + CHUNK - 1) / CHUNK;
    __syncthreads();
    s[t] = cc;
    __syncthreads();
    for (int off = 1; off < Kn; off <<= 1) {
        const int u = (t >= off) ? s[t - off] : 0;
        __syncthreads();
        s[t] += u;
        __syncthreads();
    }
    chunk_off[t] = s[t] - cc;
    if (t == Kn - 1) chunk_off[Kn] = s[t];
}

// ---------------- scatter point ids into cluster buckets
__global__ __launch_bounds__(256) void scatter_kernel(
    const int* __restrict__ assigni, int* __restrict__ cursor,
    int* __restrict__ bucket)
{
    const int p = blockIdx.x * 256 + threadIdx.x;
    const int a = assigni[p];
    const int idx = atomicAdd(&cursor[a], 1);
    bucket[idx] = p;
}

// ---------------- fused gather: per-chunk member-parallel, wave-per-member.
// Computes dist/dist_labels per member, dispersions + new_sum/new_labels partials.
__global__ __launch_bounds__(256) void fused_cluster_kernel(
    const float* __restrict__ points, const float* __restrict__ labels,
    const float* __restrict__ rlabels,
    const int* __restrict__ bucket, const int* __restrict__ offsets,
    const int* __restrict__ counts, const int* __restrict__ chunk_off,
    const float* __restrict__ tmin, const float* __restrict__ rln,
    float* __restrict__ o_dist, float* __restrict__ o_disp,
    float* __restrict__ o_dlab, float* __restrict__ o_displab,
    float* __restrict__ o_nsum, float* __restrict__ o_nlab)
{
    const int b = blockIdx.x;
    if (b >= chunk_off[Kn]) return;           // uniform early-exit

    // binary search: largest k with chunk_off[k] <= b
    int lo = 0, hi = Kn;
    while (hi - lo > 1) {
        const int mid = (lo + hi) >> 1;
        if (chunk_off[mid] <= b) lo = mid; else hi = mid;
    }
    const int k   = lo;
    const int j   = b - chunk_off[k];
    const int nk  = counts[k];
    const int beg = offsets[k] + j * CHUNK;
    const int nm  = min(nk - j * CHUNK, CHUNK);
    const bool single = (nk <= CHUNK);

    const int tid  = threadIdx.x;
    const int lane = tid & 63;
    const int w    = tid >> 6;

    __shared__ int   sidx[CHUNK];
    __shared__ __align__(16) float srl[528];   // cluster's rlabel row
    __shared__ float sacc[784];                // 256 point cols + 526 label cols
    __shared__ float sdisp[4], sdlab[4];

    for (int i = tid; i < nm; i += 256) sidx[i] = bucket[beg + i];
    for (int i = tid; i < Ln; i += 256) srl[i] = rlabels[(size_t)k * Ln + i];
    for (int i = tid; i < 784; i += 256) sacc[i] = 0.f;
    __syncthreads();

    // loop-invariant rlabel fragments for this lane (float2 layout)
    const float2 rl0 = *(const float2*)&srl[2 * lane];
    const float2 rl1 = *(const float2*)&srl[2 * (64 + lane)];
    const float2 rl2 = *(const float2*)&srl[2 * (128 + lane)];
    const float2 rl3 = *(const float2*)&srl[2 * (192 + lane)];
    float2 rlT = make_float2(0.f, 0.f);
    if (lane < 7) rlT = *(const float2*)&srl[2 * (256 + lane)];
    const float rlnk = rln[k];

    float4 accP  = make_float4(0.f, 0.f, 0.f, 0.f);
    float2 accL0 = make_float2(0.f, 0.f), accL1 = accL0,
           accL2 = accL0, accL3 = accL0, accLT = accL0;
    float dispacc = 0.f, displabacc = 0.f;

    // register double-buffered member loop: wave w handles members w, w+4, ...
    float4 pv0; float2 a0, b0_, c0, d0, e0; int p0 = 0; float t0 = 0.f;
    auto loadM = [&](int i, float4& pv, float2& a, float2& bb, float2& cc,
                     float2& dd, float2& ee, int& pid, float& tm) {
        pid = sidx[i];
        pv = ((const float4*)(points + (size_t)pid * Dn))[lane];
        const float2* l2p = (const float2*)(labels + (size_t)pid * Ln);
        a  = l2p[lane];
        bb = l2p[64 + lane];
        cc = l2p[128 + lane];
        dd = l2p[192 + lane];
        ee = (lane < 7) ? l2p[256 + lane] : make_float2(0.f, 0.f);
        tm = (lane == 0) ? tmin[pid] : 0.f;
    };

    int i = w;
    if (i < nm) loadM(i, pv0, a0, b0_, c0, d0, e0, p0, t0);
    while (i < nm) {
        const int inext = i + 4;
        float4 pv1; float2 a1, b1_, c1, d1, e1; int p1 = 0; float t1 = 0.f;
        if (inext < nm) loadM(inext, pv1, a1, b1_, c1, d1, e1, p1, t1);

        // accumulate column sums
        accP.x += pv0.x; accP.y += pv0.y; accP.z += pv0.z; accP.w += pv0.w;
        accL0.x += a0.x;  accL0.y += a0.y;
        accL1.x += b0_.x; accL1.y += b0_.y;
        accL2.x += c0.x;  accL2.y += c0.y;
        accL3.x += d0.x;  accL3.y += d0.y;
        accLT.x += e0.x;  accLT.y += e0.y;

        // per-member reductions
        float x2m = pv0.x * pv0.x + pv0.y * pv0.y + pv0.z * pv0.z + pv0.w * pv0.w;
        float l2m = a0.x * a0.x + a0.y * a0.y + b0_.x * b0_.x + b0_.y * b0_.y
                  + c0.x * c0.x + c0.y * c0.y + d0.x * d0.x + d0.y * d0.y
                  + e0.x * e0.x + e0.y * e0.y;
        float dtm = a0.x * rl0.x + a0.y * rl0.y + b0_.x * rl1.x + b0_.y * rl1.y
                  + c0.x * rl2.x + c0.y * rl2.y + d0.x * rl3.x + d0.y * rl3.y
                  + e0.x * rlT.x + e0.y * rlT.y;
#pragma unroll
        for (int off = 1; off < 64; off <<= 1) {
            x2m += __shfl_xor(x2m, off, 64);
            l2m += __shfl_xor(l2m, off, 64);
            dtm += __shfl_xor(dtm, off, 64);
        }
        if (lane == 0) {
            const float dist = x2m + t0;                 // x2 - 2 p.c + c2
            o_dist[p0] = dist;
            const float dl = 1.0f - dtm / (sqrtf(l2m) * rlnk + EPSF);
            o_dlab[p0] = dl;
            dispacc += dist;
            displabacc += dl;
        }

        pv0 = pv1; a0 = a1; b0_ = b1_; c0 = c1; d0 = d1; e0 = e1;
        p0 = p1; t0 = t1;
        i = inext;
    }

    if (lane == 0) { sdisp[w] = dispacc; sdlab[w] = displabacc; }

    // cross-wave column reduction (sequential waves, 4 barriers)
    for (int ww = 0; ww < 4; ++ww) {
        __syncthreads();
        if (w == ww) {
            float* sp = sacc;
            sp[4 * lane + 0] += accP.x;
            sp[4 * lane + 1] += accP.y;
            sp[4 * lane + 2] += accP.z;
            sp[4 * lane + 3] += accP.w;
            float* sl = sacc + 256;
            sl[2 * lane]           += accL0.x; sl[2 * lane + 1]       += accL0.y;
            sl[128 + 2 * lane]     += accL1.x; sl[128 + 2 * lane + 1] += accL1.y;
            sl[256 + 2 * lane]     += accL2.x; sl[256 + 2 * lane + 1] += accL2.y;
            sl[384 + 2 * lane]     += accL3.x; sl[384 + 2 * lane + 1] += accL3.y;
            if (lane < 7) {
                sl[512 + 2 * lane]     += accLT.x;
                sl[512 + 2 * lane + 1] += accLT.y;
            }
        }
    }
    __syncthreads();

    // write block partials (direct store if this cluster has a single chunk)
    float* np = o_nsum + (size_t)k * Dn;
    float* nl = o_nlab + (size_t)k * Ln;
    const float vP  = sacc[tid];
    const float vL0 = sacc[256 + tid];
    const float vL1 = sacc[512 + tid];
    if (single) {
        np[tid]       = vP;
        nl[tid]       = vL0;
        nl[tid + 256] = vL1;
        if (tid < 14) nl[tid + 512] = sacc[768 + tid];
    } else {
        atomicAdd(&np[tid], vP);
        atomicAdd(&nl[tid], vL0);
        atomicAdd(&nl[tid + 256], vL1);
        if (tid < 14) atomicAdd(&nl[tid + 512], sacc[768 + tid]);
    }
    if (tid == 0) {
        const float dsum  = sdisp[0] + sdisp[1] + sdisp[2] + sdisp[3];
        const float dlsum = sdlab[0] + sdlab[1] + sdlab[2] + sdlab[3];
        if (single) { o_disp[k] = dsum; o_displab[k] = dlsum; }
        else { atomicAdd(&o_disp[k], dsum); atomicAdd(&o_displab[k], dlsum); }
    }
}

extern "C" void kernel_launch(void* const* d_in, const int* in_sizes, int n_in,
                              void* d_out, int out_size, void* d_ws, size_t ws_size,
                              hipStream_t stream)
{
    const float* points    = (const float*)d_in[0];   // (B, D)
    const float* labels    = (const float*)d_in[1];   // (B, L)
    const float* centroids = (const float*)d_in[2];   // (K, D)
    const float* rlabels   = (const float*)d_in[3];   // (K, L)

    float* out = (float*)d_out;
    float* o_assign  = out;                       // B
    float* o_dist    = out + Bn;                  // B
    float* o_disp    = out + 2 * Bn;              // K
    float* o_dlab    = o_disp + Kn;               // B
    float* o_displab = o_dlab + Bn;               // K
    float* o_nsum    = o_displab + Kn;            // K*D
    float* o_nn      = o_nsum + Kn * Dn;          // K
    float* o_nlab    = o_nn + Kn;                 // K*L

    float* ws        = (float*)d_ws;
    float* c2        = ws;                          // Kn
    float* rln       = ws + Kn;                     // Kn
    float* tmin      = ws + 2 * Kn;                 // Bn
    int*   assigni   = (int*)(ws + 2 * Kn + Bn);    // Bn
    int*   counts    = assigni + Bn;                // Kn
    int*   offsets   = counts + Kn;                 // Kn
    int*   cursor    = offsets + Kn;                // Kn
    int*   bucket    = cursor + Kn;                 // Bn
    int*   chunk_off = bucket + Bn;                 // Kn+1

    // zero atomic-accumulated regions (harness poisons with 0xAA)
    hipMemsetAsync(counts, 0, Kn * sizeof(int), stream);
    hipMemsetAsync(o_disp, 0, Kn * sizeof(float), stream);
    hipMemsetAsync(o_displab, 0, Kn * sizeof(float), stream);
    hipMemsetAsync(o_nsum, 0, (size_t)Kn * Dn * sizeof(float), stream);
    hipMemsetAsync(o_nlab, 0, (size_t)Kn * Ln * sizeof(float), stream);

    prep_kernel<<<Kn, 256, 0, stream>>>(centroids, rlabels, c2, rln);
    assign_kernel<<<Bn / BM, 256, 0, stream>>>(points, centroids, c2,
                                               o_assign, assigni, tmin);
    count_kernel<<<Bn / 256, 256, 0, stream>>>(assigni, counts);
    scan_kernel<<<1, Kn, 0, stream>>>(counts, offsets, cursor, o_nn, chunk_off);
    scatter_kernel<<<Bn / 256, 256, 0, stream>>>(assigni, cursor, bucket);
    fused_cluster_kernel<<<MAXCHUNKS, 256, 0, stream>>>(
        points, labels, rlabels, bucket, offsets, counts, chunk_off,
        tmin, rln, o_dist, o_disp, o_dlab, o_displab, o_nsum, o_nlab);
}

// Round 2
// 796.623 us; speedup vs baseline: 1.7552x; 1.0318x over previous
//
#include <hip/hip_runtime.h>
#include <float.h>
#include <math.h>

// Problem constants (fixed by setup_inputs)
constexpr int Bn = 131072;  // points
constexpr int Dn = 256;     // feature dim
constexpr int Kn = 1024;    // clusters
constexpr int Ln = 526;     // label dim
constexpr float EPSF = 1e-8f;

constexpr int CHUNK = 128;                    // members per fused-kernel block
constexpr int MAXCHUNKS = Bn / CHUNK + Kn;    // 2048: sum ceil(n_k/C) <= B/C + K

// ---- assign kernel tiling (split-f16 MFMA GEMM) ----
constexpr int BM  = 128;        // points per block
constexpr int BN  = 128;        // centroids per n-tile
constexpr int KC  = 32;         // K per chunk (f16 MFMA 16x16x32)
constexpr int NT  = Kn / BN;    // 8 n-tiles
constexpr int KCH = Dn / KC;    // 8 k-chunks
constexpr int NCH = NT * KCH;   // 64 chunks total

typedef _Float16 f16x8 __attribute__((ext_vector_type(8)));
typedef _Float16 f16x4 __attribute__((ext_vector_type(4)));
typedef float    f32x4 __attribute__((ext_vector_type(4)));

// LDS tile: per buf, A and B planes of [128 rows][64 f16 = hi32|lo32] (128 B rows).
// 16-B slot q within a row holds logical slot q ^ (row&7)  (XOR swizzle, both sides).
union SMemU {
    _Float16 tiles[2][2][BM][64];               // 65536 B
    struct { float t[BM][2]; int k[BM][2]; } red;
};

__device__ __forceinline__ void dma16(const void* g, void* l) {
    __builtin_amdgcn_global_load_lds(
        (const __attribute__((address_space(1))) unsigned int*)g,
        (__attribute__((address_space(3))) unsigned int*)l, 16, 0, 0);
}

// ---------------- prep: c2[k], rln[k], and pack centroids to f16 hi/lo granules.
// cpk layout: [(k*8 + kchunk)*64 + j] j<32: hi, j>=32: lo  (128 B per (k,chunk))
__global__ __launch_bounds__(256) void prep_kernel(
    const float* __restrict__ centroids, const float* __restrict__ rlabels,
    float* __restrict__ c2, float* __restrict__ rln, _Float16* __restrict__ cpk)
{
    const int k = blockIdx.x;
    const int t = threadIdx.x;
    float v = centroids[k * Dn + t];            // Dn == blockDim
    // pack split-f16
    {
        const int c = t >> 5, j = t & 31;
        const _Float16 h = (_Float16)v;
        const _Float16 l = (_Float16)(v - (float)h);
        cpk[((size_t)k * KCH + c) * 64 + j]      = h;
        cpk[((size_t)k * KCH + c) * 64 + 32 + j] = l;
    }
    float s1 = v * v;
    float s2 = 0.f;
    for (int i = t; i < Ln; i += 256) {
        float u = rlabels[(size_t)k * Ln + i];
        s2 += u * u;
    }
    for (int off = 32; off > 0; off >>= 1) {
        s1 += __shfl_down(s1, off, 64);
        s2 += __shfl_down(s2, off, 64);
    }
    __shared__ float red[8];
    const int wv = t >> 6;
    if ((t & 63) == 0) { red[wv * 2] = s1; red[wv * 2 + 1] = s2; }
    __syncthreads();
    if (t == 0) {
        c2[k]  = red[0] + red[2] + red[4] + red[6];
        rln[k] = sqrtf(red[1] + red[3] + red[5] + red[7]);
    }
}

// ---------------- assignment: split-f16 MFMA GEMM, 128 points x 1024 centroids.
// B staged via global_load_lds DMA from pre-packed cpk (source pre-swizzled);
// A reg-staged + converted once per block, written via swizzled ds_write_b128.
__global__ __launch_bounds__(256, 2) void assign_kernel(
    const float* __restrict__ points, const _Float16* __restrict__ cpk,
    const float* __restrict__ c2,
    float* __restrict__ o_assign, int* __restrict__ ws_assign,
    float* __restrict__ ws_tmin, int* __restrict__ counts)
{
    __shared__ __align__(16) SMemU sm;
    const int tid  = threadIdx.x;
    const int lane = tid & 63;
    const int wid  = tid >> 6;
    const int wrow = wid >> 1;          // which 64-point half
    const int wcol = wid & 1;           // which 64-centroid half of the n-tile
    const int ln15 = lane & 15;
    const int g    = lane >> 4;         // k-slot group (8 f16 each)
    const int bm0  = blockIdx.x * BM;

    // A staging mapping: thread -> (row, half of 32 k)
    const int arow  = tid >> 1;
    const int ahalf = tid & 1;
    const int r7a   = arow & 7;
    const int s0a   = ahalf * 2;        // hi slots {s0a, s0a+1}, lo +4

    // B DMA mapping
    const int rowl = lane >> 3;         // row within 8-row piece
    const int q8   = lane & 7;          // linear 16B slot within row

    f32x4 acc[4][4];
#pragma unroll
    for (int i = 0; i < 4; ++i)
#pragma unroll
        for (int j = 0; j < 4; ++j)
#pragma unroll
            for (int r = 0; r < 4; ++r) acc[i][j][r] = 0.f;

    float mint[16];
    int   mink[16];
#pragma unroll
    for (int s = 0; s < 16; ++s) { mint[s] = FLT_MAX; mink[s] = 0; }

    float4 pa[4];
    auto loadA = [&](int t) {
        const int kc = t & 7;
        const float* ap = points + (size_t)(bm0 + arow) * Dn + kc * KC + ahalf * 16;
        pa[0] = *(const float4*)(ap);
        pa[1] = *(const float4*)(ap + 4);
        pa[2] = *(const float4*)(ap + 8);
        pa[3] = *(const float4*)(ap + 12);
    };
    auto dmaB = [&](int t, int buf) {
        const int nt = t >> 3, kc = t & 7;
#pragma unroll
        for (int jj = 0; jj < 4; ++jj) {
            const int p  = wid * 4 + jj;            // piece 0..15, 8 rows each
            const int br = p * 8 + rowl;            // B row 0..127
            const int srcslot = q8 ^ (br & 7);      // pre-swizzled source
            const _Float16* gp = cpk
                + ((size_t)(nt * BN + br) * KCH + kc) * 64 + srcslot * 8;
            dma16(gp, &sm.tiles[buf][1][p * 8][0]); // wave-uniform LDS base
        }
    };
    auto writeA = [&](int buf) {
        _Float16* Ar = &sm.tiles[buf][0][arow][0];
        const float vs[16] = {pa[0].x, pa[0].y, pa[0].z, pa[0].w,
                              pa[1].x, pa[1].y, pa[1].z, pa[1].w,
                              pa[2].x, pa[2].y, pa[2].z, pa[2].w,
                              pa[3].x, pa[3].y, pa[3].z, pa[3].w};
        f16x8 h0, h1, l0, l1;
#pragma unroll
        for (int u = 0; u < 8; ++u) {
            h0[u] = (_Float16)vs[u];     l0[u] = (_Float16)(vs[u]     - (float)h0[u]);
            h1[u] = (_Float16)vs[8 + u]; l1[u] = (_Float16)(vs[8 + u] - (float)h1[u]);
        }
        *(f16x8*)&Ar[((s0a    ) ^ r7a) * 8] = h0;
        *(f16x8*)&Ar[((s0a + 1) ^ r7a) * 8] = h1;
        *(f16x8*)&Ar[((s0a + 4) ^ r7a) * 8] = l0;
        *(f16x8*)&Ar[((s0a + 5) ^ r7a) * 8] = l1;
    };

    // prologue: stage chunk 0
    loadA(0);
    dmaB(0, 0);
    writeA(0);
    __syncthreads();

    for (int t = 0; t < NCH; ++t) {
        const int buf = t & 1;
        const bool more = (t + 1) < NCH;
        if (more) { loadA(t + 1); dmaB(t + 1, buf ^ 1); }

        // fragment loads (swizzled slots): hi slot g, lo slot g+4
        f16x8 ah[4], al[4], bh[4], bl[4];
#pragma unroll
        for (int mi = 0; mi < 4; ++mi) {
            const int r  = wrow * 64 + mi * 16 + ln15;
            const int r7 = r & 7;
            const _Float16* Ar = &sm.tiles[buf][0][r][0];
            ah[mi] = *(const f16x8*)&Ar[((g    ) ^ r7) * 8];
            al[mi] = *(const f16x8*)&Ar[((g + 4) ^ r7) * 8];
        }
#pragma unroll
        for (int nj = 0; nj < 4; ++nj) {
            const int r  = wcol * 64 + nj * 16 + ln15;
            const int r7 = r & 7;
            const _Float16* Br = &sm.tiles[buf][1][r][0];
            bh[nj] = *(const f16x8*)&Br[((g    ) ^ r7) * 8];
            bl[nj] = *(const f16x8*)&Br[((g + 4) ^ r7) * 8];
        }
#pragma unroll
        for (int mi = 0; mi < 4; ++mi)
#pragma unroll
            for (int nj = 0; nj < 4; ++nj) {
                acc[mi][nj] = __builtin_amdgcn_mfma_f32_16x16x32_f16(
                    al[mi], bh[nj], acc[mi][nj], 0, 0, 0);
                acc[mi][nj] = __builtin_amdgcn_mfma_f32_16x16x32_f16(
                    ah[mi], bl[nj], acc[mi][nj], 0, 0, 0);
                acc[mi][nj] = __builtin_amdgcn_mfma_f32_16x16x32_f16(
                    ah[mi], bh[nj], acc[mi][nj], 0, 0, 0);
            }

        if ((t & 7) == 7) {
            // n-tile complete: fold into running argmin using C/D layout
            // (col = lane&15 -> centroid, row = (lane>>4)*4 + reg -> point)
            const int nt = t >> 3;
            const int nb = nt * BN + wcol * 64 + ln15;
#pragma unroll
            for (int nj = 0; nj < 4; ++nj) {
                const int n = nb + nj * 16;
                const float c2n = c2[n];
#pragma unroll
                for (int mi = 0; mi < 4; ++mi)
#pragma unroll
                    for (int r = 0; r < 4; ++r) {
                        const float tv = fmaf(-2.f, acc[mi][nj][r], c2n);
                        const int s = mi * 4 + r;
                        if (tv < mint[s] || (tv == mint[s] && n < mink[s])) {
                            mint[s] = tv; mink[s] = n;
                        }
                        acc[mi][nj][r] = 0.f;
                    }
            }
        }

        if (more) {
            writeA(buf ^ 1);
            __syncthreads();
        }
    }

    // cross-lane argmin over the 16 centroid-columns (low 4 lane bits)
#pragma unroll
    for (int s = 0; s < 16; ++s) {
        float tv = mint[s]; int kv = mink[s];
#pragma unroll
        for (int off = 1; off < 16; off <<= 1) {
            const float to = __shfl_xor(tv, off, 64);
            const int   ko = __shfl_xor(kv, off, 64);
            if (to < tv || (to == tv && ko < kv)) { tv = to; kv = ko; }
        }
        mint[s] = tv; mink[s] = kv;
    }
    __syncthreads();   // all waves done reading planes; safe to reuse LDS
    if (ln15 == 0) {
#pragma unroll
        for (int s = 0; s < 16; ++s) {
            const int pr = wrow * 64 + (s >> 2) * 16 + g * 4 + (s & 3);
            sm.red.t[pr][wcol] = mint[s];
            sm.red.k[pr][wcol] = mink[s];
        }
    }
    __syncthreads();
    if (tid < BM) {
        float bt = sm.red.t[tid][0];
        int   bk = sm.red.k[tid][0];
        const float t1 = sm.red.t[tid][1];
        const int   k1 = sm.red.k[tid][1];
        if (t1 < bt || (t1 == bt && k1 < bk)) { bt = t1; bk = k1; }
        o_assign[bm0 + tid]  = (float)bk;
        ws_assign[bm0 + tid] = bk;
        ws_tmin[bm0 + tid]   = bt;
        atomicAdd(&counts[bk], 1);     // fused histogram (count_kernel removed)
    }
}

// ---------------- exclusive scans over Kn=1024: counts and chunk counts
__global__ __launch_bounds__(1024) void scan_kernel(
    const int* __restrict__ counts, int* __restrict__ offsets,
    int* __restrict__ cursor, float* __restrict__ o_nn,
    int* __restrict__ chunk_off)
{
    __shared__ int s[Kn];
    const int t = threadIdx.x;
    const int c = counts[t];
    o_nn[t] = (float)c;
    s[t] = c;
    __syncthreads();
    for (int off = 1; off < Kn; off <<= 1) {
        const int u = (t >= off) ? s[t - off] : 0;
        __syncthreads();
        s[t] += u;
        __syncthreads();
    }
    const int excl = s[t] - c;
    offsets[t] = excl;
    cursor[t]  = excl;

    // second scan: chunks per cluster
    const int cc = (c + CHUNK - 1) / CHUNK;
    __syncthreads();
    s[t] = cc;
    __syncthreads();
    for (int off = 1; off < Kn; off <<= 1) {
        const int u = (t >= off) ? s[t - off] : 0;
        __syncthreads();
        s[t] += u;
        __syncthreads();
    }
    chunk_off[t] = s[t] - cc;
    if (t == Kn - 1) chunk_off[Kn] = s[t];
}

// ---------------- scatter point ids into cluster buckets
__global__ __launch_bounds__(256) void scatter_kernel(
    const int* __restrict__ assigni, int* __restrict__ cursor,
    int* __restrict__ bucket)
{
    const int p = blockIdx.x * 256 + threadIdx.x;
    const int a = assigni[p];
    const int idx = atomicAdd(&cursor[a], 1);
    bucket[idx] = p;
}

// ---------------- fused gather: per-chunk member-parallel, wave-per-member.
// Depth-2 member prefetch (gather is HBM-latency-bound); LDS-atomic column sums.
__global__ __launch_bounds__(256) void fused_cluster_kernel(
    const float* __restrict__ points, const float* __restrict__ labels,
    const float* __restrict__ rlabels,
    const int* __restrict__ bucket, const int* __restrict__ offsets,
    const int* __restrict__ counts, const int* __restrict__ chunk_off,
    const float* __restrict__ tmin, const float* __restrict__ rln,
    float* __restrict__ o_dist, float* __restrict__ o_disp,
    float* __restrict__ o_dlab, float* __restrict__ o_displab,
    float* __restrict__ o_nsum, float* __restrict__ o_nlab)
{
    const int b = blockIdx.x;
    if (b >= chunk_off[Kn]) return;           // uniform early-exit

    // binary search: largest k with chunk_off[k] <= b
    int lo = 0, hi = Kn;
    while (hi - lo > 1) {
        const int mid = (lo + hi) >> 1;
        if (chunk_off[mid] <= b) lo = mid; else hi = mid;
    }
    const int k   = lo;
    const int j   = b - chunk_off[k];
    const int nk  = counts[k];
    const int beg = offsets[k] + j * CHUNK;
    const int nm  = min(nk - j * CHUNK, CHUNK);
    const bool single = (nk <= CHUNK);

    const int tid  = threadIdx.x;
    const int lane = tid & 63;
    const int w    = tid >> 6;

    __shared__ int   sidx[CHUNK];
    __shared__ __align__(16) float srl[528];   // cluster's rlabel row
    __shared__ float sacc[784];                // 256 point cols + 526 label cols
    __shared__ float sdisp[4], sdlab[4];

    for (int i = tid; i < nm; i += 256) sidx[i] = bucket[beg + i];
    for (int i = tid; i < Ln; i += 256) srl[i] = rlabels[(size_t)k * Ln + i];
    for (int i = tid; i < 784; i += 256) sacc[i] = 0.f;
    __syncthreads();

    // loop-invariant rlabel fragments for this lane (float2 layout)
    const float2 rl0 = *(const float2*)&srl[2 * lane];
    const float2 rl1 = *(const float2*)&srl[2 * (64 + lane)];
    const float2 rl2 = *(const float2*)&srl[2 * (128 + lane)];
    const float2 rl3 = *(const float2*)&srl[2 * (192 + lane)];
    float2 rlT = make_float2(0.f, 0.f);
    if (lane < 7) rlT = *(const float2*)&srl[2 * (256 + lane)];
    const float rlnk = rln[k];

    float4 accP  = make_float4(0.f, 0.f, 0.f, 0.f);
    float2 accL0 = make_float2(0.f, 0.f), accL1 = accL0,
           accL2 = accL0, accL3 = accL0, accLT = accL0;
    float dispacc = 0.f, displabacc = 0.f;

    auto loadM = [&](int i, float4& pv, float2& a, float2& bb, float2& cc,
                     float2& dd, float2& ee, int& pid, float& tm) {
        pid = sidx[i];
        pv = ((const float4*)(points + (size_t)pid * Dn))[lane];
        const float2* l2p = (const float2*)(labels + (size_t)pid * Ln);
        a  = l2p[lane];
        bb = l2p[64 + lane];
        cc = l2p[128 + lane];
        dd = l2p[192 + lane];
        ee = (lane < 7) ? l2p[256 + lane] : make_float2(0.f, 0.f);
        tm = (lane == 0) ? tmin[pid] : 0.f;
    };

    // depth-2 register pipeline: wave w handles members w, w+4, ...
    float4 pv0 = make_float4(0,0,0,0), pv1 = pv0, pvX = pv0;
    float2 z2 = make_float2(0.f, 0.f);
    float2 a0 = z2, b0_ = z2, c0 = z2, d0 = z2, e0 = z2;
    float2 a1 = z2, b1_ = z2, c1 = z2, d1 = z2, e1 = z2;
    float2 aX = z2, bX_ = z2, cX = z2, dX = z2, eX = z2;
    int p0 = 0, p1 = 0, pX = 0; float t0 = 0.f, t1 = 0.f, tX = 0.f;

    int i = w;
    if (i < nm)     loadM(i,     pv0, a0, b0_, c0, d0, e0, p0, t0);
    if (i + 4 < nm) loadM(i + 4, pv1, a1, b1_, c1, d1, e1, p1, t1);
    while (i < nm) {
        if (i + 8 < nm) loadM(i + 8, pvX, aX, bX_, cX, dX, eX, pX, tX);

        // accumulate column sums
        accP.x += pv0.x; accP.y += pv0.y; accP.z += pv0.z; accP.w += pv0.w;
        accL0.x += a0.x;  accL0.y += a0.y;
        accL1.x += b0_.x; accL1.y += b0_.y;
        accL2.x += c0.x;  accL2.y += c0.y;
        accL3.x += d0.x;  accL3.y += d0.y;
        accLT.x += e0.x;  accLT.y += e0.y;

        // per-member reductions
        float x2m = pv0.x * pv0.x + pv0.y * pv0.y + pv0.z * pv0.z + pv0.w * pv0.w;
        float l2m = a0.x * a0.x + a0.y * a0.y + b0_.x * b0_.x + b0_.y * b0_.y
                  + c0.x * c0.x + c0.y * c0.y + d0.x * d0.x + d0.y * d0.y
                  + e0.x * e0.x + e0.y * e0.y;
        float dtm = a0.x * rl0.x + a0.y * rl0.y + b0_.x * rl1.x + b0_.y * rl1.y
                  + c0.x * rl2.x + c0.y * rl2.y + d0.x * rl3.x + d0.y * rl3.y
                  + e0.x * rlT.x + e0.y * rlT.y;
#pragma unroll
        for (int off = 1; off < 64; off <<= 1) {
            x2m += __shfl_xor(x2m, off, 64);
            l2m += __shfl_xor(l2m, off, 64);
            dtm += __shfl_xor(dtm, off, 64);
        }
        if (lane == 0) {
            const float dist = x2m + t0;                 // x2 - 2 p.c + c2
            o_dist[p0] = dist;
            const float dl = 1.0f - dtm / (sqrtf(l2m) * rlnk + EPSF);
            o_dlab[p0] = dl;
            dispacc += dist;
            displabacc += dl;
        }

        pv0 = pv1; a0 = a1; b0_ = b1_; c0 = c1; d0 = d1; e0 = e1; p0 = p1; t0 = t1;
        pv1 = pvX; a1 = aX; b1_ = bX_; c1 = cX; d1 = dX; e1 = eX; p1 = pX; t1 = tX;
        i += 4;
    }

    if (lane == 0) { sdisp[w] = dispacc; sdlab[w] = displabacc; }

    // cross-wave column reduction via LDS float atomics (no wave serialization)
    {
        atomicAdd(&sacc[4 * lane + 0], accP.x);
        atomicAdd(&sacc[4 * lane + 1], accP.y);
        atomicAdd(&sacc[4 * lane + 2], accP.z);
        atomicAdd(&sacc[4 * lane + 3], accP.w);
        float* sl = sacc + 256;
        atomicAdd(&sl[2 * lane],           accL0.x); atomicAdd(&sl[2 * lane + 1],       accL0.y);
        atomicAdd(&sl[128 + 2 * lane],     accL1.x); atomicAdd(&sl[128 + 2 * lane + 1], accL1.y);
        atomicAdd(&sl[256 + 2 * lane],     accL2.x); atomicAdd(&sl[256 + 2 * lane + 1], accL2.y);
        atomicAdd(&sl[384 + 2 * lane],     accL3.x); atomicAdd(&sl[384 + 2 * lane + 1], accL3.y);
        if (lane < 7) {
            atomicAdd(&sl[512 + 2 * lane],     accLT.x);
            atomicAdd(&sl[512 + 2 * lane + 1], accLT.y);
        }
    }
    __syncthreads();

    // write block partials (direct store if this cluster has a single chunk)
    float* np = o_nsum + (size_t)k * Dn;
    float* nl = o_nlab + (size_t)k * Ln;
    const float vP  = sacc[tid];
    const float vL0 = sacc[256 + tid];
    const float vL1 = sacc[512 + tid];
    if (single) {
        np[tid]       = vP;
        nl[tid]       = vL0;
        nl[tid + 256] = vL1;
        if (tid < 14) nl[tid + 512] = sacc[768 + tid];
    } else {
        atomicAdd(&np[tid], vP);
        atomicAdd(&nl[tid], vL0);
        atomicAdd(&nl[tid + 256], vL1);
        if (tid < 14) atomicAdd(&nl[tid + 512], sacc[768 + tid]);
    }
    if (tid == 0) {
        const float dsum  = sdisp[0] + sdisp[1] + sdisp[2] + sdisp[3];
        const float dlsum = sdlab[0] + sdlab[1] + sdlab[2] + sdlab[3];
        if (single) { o_disp[k] = dsum; o_displab[k] = dlsum; }
        else { atomicAdd(&o_disp[k], dsum); atomicAdd(&o_displab[k], dlsum); }
    }
}

extern "C" void kernel_launch(void* const* d_in, const int* in_sizes, int n_in,
                              void* d_out, int out_size, void* d_ws, size_t ws_size,
                              hipStream_t stream)
{
    const float* points    = (const float*)d_in[0];   // (B, D)
    const float* labels    = (const float*)d_in[1];   // (B, L)
    const float* centroids = (const float*)d_in[2];   // (K, D)
    const float* rlabels   = (const float*)d_in[3];   // (K, L)

    float* out = (float*)d_out;
    float* o_assign  = out;                       // B
    float* o_dist    = out + Bn;                  // B
    float* o_disp    = out + 2 * Bn;              // K
    float* o_dlab    = o_disp + Kn;               // B
    float* o_displab = o_dlab + Bn;               // K
    float* o_nsum    = o_displab + Kn;            // K*D
    float* o_nn      = o_nsum + Kn * Dn;          // K
    float* o_nlab    = o_nn + Kn;                 // K*L

    float* ws        = (float*)d_ws;
    float* c2        = ws;                          // Kn
    float* rln       = ws + Kn;                     // Kn
    float* tmin      = ws + 2 * Kn;                 // Bn
    int*   assigni   = (int*)(ws + 2 * Kn + Bn);    // Bn
    int*   counts    = assigni + Bn;                // Kn
    int*   offsets   = counts + Kn;                 // Kn
    int*   cursor    = offsets + Kn;                // Kn
    int*   bucket    = cursor + Kn;                 // Bn
    int*   chunk_off = bucket + Bn;                 // Kn+1
    _Float16* cpk    = (_Float16*)(ws + 400000);    // Kn*512 f16 = 1 MB, 16B-aligned

    // zero atomic-accumulated regions (harness poisons with 0xAA)
    hipMemsetAsync(counts, 0, Kn * sizeof(int), stream);
    hipMemsetAsync(o_disp, 0, Kn * sizeof(float), stream);
    hipMemsetAsync(o_displab, 0, Kn * sizeof(float), stream);
    hipMemsetAsync(o_nsum, 0, (size_t)Kn * Dn * sizeof(float), stream);
    hipMemsetAsync(o_nlab, 0, (size_t)Kn * Ln * sizeof(float), stream);

    prep_kernel<<<Kn, 256, 0, stream>>>(centroids, rlabels, c2, rln, cpk);
    assign_kernel<<<Bn / BM, 256, 0, stream>>>(points, cpk, c2,
                                               o_assign, assigni, tmin, counts);
    scan_kernel<<<1, Kn, 0, stream>>>(counts, offsets, cursor, o_nn, chunk_off);
    scatter_kernel<<<Bn / 256, 256, 0, stream>>>(assigni, cursor, bucket);
    fused_cluster_kernel<<<MAXCHUNKS, 256, 0, stream>>>(
        points, labels, rlabels, bucket, offsets, counts, chunk_off,
        tmin, rln, o_dist, o_disp, o_dlab, o_displab, o_nsum, o_nlab);
}